// Round 10
// baseline (15.197 us; speedup 1.0000x reference)
//
#include <hip/hip_runtime.h>
#include <math.h>

// Problem constants (from reference): B=16, D=128, T=512.
#define B_DIM 16
#define D_DIM 128
#define T_DIM 512
#define NT4   128        // float4 per T-row
#define CSCALE 8.6316745750453727e-05f   // 1/(512*sqrt(512)) : DC/T * softmax scale

// ---------------------------------------------------------------------------
// One dispatch, 256 blocks x 512 threads.
// Block = (b = bid&15, rest = bid>>4 in 0..15): i-tile = (rest>>1)*16 (EIGHT
// 16-row tiles -> all 128 rows covered; R9's bug was 8-row tiles here),
// t-half = rest&1.  bid ≡ b (mod 16) keeps batch b on XCD b%8 (keys L2-reuse).
//
// Per-block traffic: keys 256 KB (full ksum, irreducible without cross-block
// sync; R4/R5/R7 showed any sync costs >= 25 us) + values 128 KB (own t-half
// only) + Q 32 KB = 416 KB (-21% vs R3's 528 KB).
//
// Phase A: ksum for all 128 j: 8 waves x 4 iters x 4 rows, quad pattern
//          (16 lanes/row, coalesced), 4-level shfl_xor.
// Phase B: qsum of rows 2wv, 2wv+1 (full-wave reduce each).
// Phase C: softmax of rows 2wv, 2wv+1, no max-subtract (|logit| <= ~0.7):
//          logit = para0*CSCALE * qsum_i * ksum_j * para2_ij
//          (irfft().mean() keeps only the DC bin / T). s_w[j][r] transposed.
// Phase D: out[b, i0..i0+16, t-half] = attn x values[:, t-half]:
//          thread = (jq 0..3, rh 0..1, t4 0..63); each wave = one (jq,rh),
//          rows rh*8..rh*8+7; 4-way jq combine through LDS (64 KB).
// ---------------------------------------------------------------------------
__global__ __launch_bounds__(512) void fused_attn_kernel(
    const float* __restrict__ queries,
    const float* __restrict__ keys,
    const float* __restrict__ values,
    const float* __restrict__ para,
    const float* __restrict__ para2,
    float* __restrict__ out) {

    int bid  = blockIdx.x;
    int b    = bid & 15;
    int rest = bid >> 4;            // 0..15
    int i0   = (rest >> 1) * 16;    // 16-row i-tile: 0,16,...,112
    int tq   = rest & 1;            // t-half: f4 columns [tq*64, tq*64+64)
    int tid  = threadIdx.x;
    int wv   = tid >> 6;
    int ln   = tid & 63;

    __shared__ float  s_ksum[D_DIM];
    __shared__ float  s_q[16];
    __shared__ float  s_w[D_DIM][16];       // transposed: [j][row], 8 KB
    __shared__ float4 s_part[4][16][64];    // 64 KB combine buffer

    const float4* k4 = reinterpret_cast<const float4*>(keys)   + (size_t)b * D_DIM * NT4;
    const float4* v4 = reinterpret_cast<const float4*>(values) + (size_t)b * D_DIM * NT4;

    // ---- Phase A: ksum for all 128 rows ----
    {
        int rr = ln >> 4;      // row within quad (0..3)
        int cc = ln & 15;      // column chunk (0..15)
        #pragma unroll
        for (int it = 0; it < 4; ++it) {
            int row = it * 32 + wv * 4 + rr;
            const float4* kr = k4 + (size_t)row * NT4;
            float s = 0.f;
            #pragma unroll
            for (int k = 0; k < 8; ++k) {
                float4 v = kr[cc + k * 16];
                s += (v.x + v.y) + (v.z + v.w);
            }
            s += __shfl_xor(s, 1, 64);
            s += __shfl_xor(s, 2, 64);
            s += __shfl_xor(s, 4, 64);
            s += __shfl_xor(s, 8, 64);
            if (cc == 0) s_ksum[row] = s;
        }
    }

    // ---- Phase B: qsum of rows i0+2wv, i0+2wv+1 ----
    #pragma unroll
    for (int rr = 0; rr < 2; ++rr) {
        int r = wv * 2 + rr;
        const float4* qr = reinterpret_cast<const float4*>(queries)
                           + (size_t)(b * D_DIM + i0 + r) * NT4;
        float4 a = qr[ln];
        float4 d = qr[ln + 64];
        float s = (a.x + a.y) + (a.z + a.w) + (d.x + d.y) + (d.z + d.w);
        #pragma unroll
        for (int off = 32; off > 0; off >>= 1) s += __shfl_xor(s, off, 64);
        if (ln == 0) s_q[r] = s;
    }
    __syncthreads();

    // ---- Phase C: softmax of rows i0+2wv, i0+2wv+1 (no max-subtract) ----
    #pragma unroll
    for (int rr = 0; rr < 2; ++rr) {
        int r = wv * 2 + rr;
        float qc = s_q[r] * (para[0] * CSCALE);
        const float* p2 = para2 + (size_t)(i0 + r) * D_DIM;
        float l0 = qc * s_ksum[ln] * p2[ln];
        float l1 = qc * s_ksum[ln + 64] * p2[ln + 64];
        float e0 = __expf(l0);
        float e1 = __expf(l1);
        float s = e0 + e1;
        #pragma unroll
        for (int off = 32; off > 0; off >>= 1) s += __shfl_xor(s, off, 64);
        float inv = 1.0f / s;
        s_w[ln][r] = e0 * inv;
        s_w[ln + 64][r] = e1 * inv;
    }
    __syncthreads();

    // ---- Phase D: t-half matmul, 16 rows ----
    int jq = tid >> 7;              // j-quarter 0..3
    int rh = (tid >> 6) & 1;        // row-half: rows rh*8..rh*8+7
    int t4 = tid & 63;              // f4 column within the t-half
    int col = tq * 64 + t4;

    float4 acc[8];
    #pragma unroll
    for (int r = 0; r < 8; ++r) acc[r] = make_float4(0.f, 0.f, 0.f, 0.f);

    #define FMA4(A, W) \
        A.x += (W) * v.x; A.y += (W) * v.y; A.z += (W) * v.z; A.w += (W) * v.w;

    int jbeg = jq * 32;
    #pragma unroll 8
    for (int j = jbeg; j < jbeg + 32; ++j) {
        float4 v = v4[(size_t)j * NT4 + col];
        const float4* wp = reinterpret_cast<const float4*>(&s_w[j][rh * 8]);  // wave-uniform
        float4 w0 = wp[0];
        float4 w1 = wp[1];
        FMA4(acc[0], w0.x) FMA4(acc[1], w0.y) FMA4(acc[2], w0.z) FMA4(acc[3], w0.w)
        FMA4(acc[4], w1.x) FMA4(acc[5], w1.y) FMA4(acc[6], w1.z) FMA4(acc[7], w1.w)
    }
    #undef FMA4

    #pragma unroll
    for (int r = 0; r < 8; ++r) s_part[jq][rh * 8 + r][t4] = acc[r];
    __syncthreads();

    // combine 4 jq-partials; 16 rows x 64 cols = 1024 f4, 2 per thread
    #pragma unroll
    for (int k = 0; k < 2; ++k) {
        int idx = tid + k * 512;
        int r  = idx >> 6;          // 0..15
        int tt = idx & 63;
        float4 p0 = s_part[0][r][tt];
        float4 p1 = s_part[1][r][tt];
        float4 p2 = s_part[2][r][tt];
        float4 p3 = s_part[3][r][tt];
        float4 sum;
        sum.x = (p0.x + p1.x) + (p2.x + p3.x);
        sum.y = (p0.y + p1.y) + (p2.y + p3.y);
        sum.z = (p0.z + p1.z) + (p2.z + p3.z);
        sum.w = (p0.w + p1.w) + (p2.w + p3.w);
        reinterpret_cast<float4*>(out)[(size_t)(b * D_DIM + i0 + r) * NT4 + tq * 64 + tt] = sum;
    }
}

extern "C" void kernel_launch(void* const* d_in, const int* in_sizes, int n_in,
                              void* d_out, int out_size, void* d_ws, size_t ws_size,
                              hipStream_t stream) {
    const float* queries = (const float*)d_in[0];  // [B, D, T]
    const float* keys    = (const float*)d_in[1];  // [B, D, T]
    const float* values  = (const float*)d_in[2];  // [B, D, T]
    // d_in[3] = attn_mask (unused)
    const float* para    = (const float*)d_in[4];  // [25]
    const float* para2   = (const float*)d_in[5];  // [D, D]
    float* out = (float*)d_out;                    // [B, D, T] fp32

    fused_attn_kernel<<<256, 512, 0, stream>>>(queries, keys, values, para, para2, out);
}